// Round 2
// baseline (276.747 us; speedup 1.0000x reference)
//
#include <hip/hip_runtime.h>
#include <hip/hip_bf16.h>
#include <stdint.h>

// Problem dims (fixed): B=4, S=2048, IN=1024, OUT=4096 -> M=8192, K=1024, N=4096
#define M_DIM 8192
#define K_DIM 1024
#define N_DIM 4096

typedef __bf16 bf16x8 __attribute__((ext_vector_type(8)));
typedef float  f32x4  __attribute__((ext_vector_type(4)));

__device__ __forceinline__ uint16_t f2bf(float f) {
  union { float f; uint32_t u; } x; x.f = f;
  uint32_t u = x.u;
  return (uint16_t)((u + 0x7FFFu + ((u >> 16) & 1u)) >> 16);  // RNE
}

// ---------------- kernel 1: input fp32 -> bf16 ----------------
__global__ __launch_bounds__(256) void convert_bf16_kernel(
    const float* __restrict__ in, uint16_t* __restrict__ out, int n4) {
  int i = blockIdx.x * 256 + threadIdx.x;
  if (i >= n4) return;
  float4 v = ((const float4*)in)[i];
  ushort4 o;
  o.x = f2bf(v.x); o.y = f2bf(v.y); o.z = f2bf(v.z); o.w = f2bf(v.w);
  ((ushort4*)out)[i] = o;
}

// ---------------- kernel 2: fold everything into W5^T (N x K) bf16 ----------------
// One thread per (in-pair m_in, out-pair m_out): computes a 2x2 block of W5.
// (validated in R1: absmax 0.0156 vs threshold 0.0522)
__global__ __launch_bounds__(256) void build_w_kernel(
    const float* __restrict__ weight,      // (4096, 1024)
    const float* __restrict__ mask,        // (4096, 1024)
    const float* __restrict__ in_scores,   // (512)
    const float* __restrict__ out_scores,  // (2048)
    const int*   __restrict__ in_mapping,  // (1024)
    const int*   __restrict__ out_mapping, // (4096)
    uint16_t*    __restrict__ w5t)         // (4096, 1024) bf16: row=o, col=i
{
  int tid  = blockIdx.x * 256 + threadIdx.x;     // [0, 512*2048)
  int m_in  = tid & 511;
  int m_out = tid >> 9;

  float ai = in_scores[m_in];
  float ao = out_scores[m_out];
  float si = sinf(ai), ci = cosf(ai);
  float so = sinf(ao), co = cosf(ao);

  int ia0 = in_mapping[2 * m_in];
  int ia1 = in_mapping[2 * m_in + 1];
  int r0  = out_mapping[2 * m_out];
  int r1  = out_mapping[2 * m_out + 1];

  float w00 = weight[(size_t)r0 * K_DIM + ia0];
  float w01 = weight[(size_t)r0 * K_DIM + ia1];
  float w10 = weight[(size_t)r1 * K_DIM + ia0];
  float w11 = weight[(size_t)r1 * K_DIM + ia1];

  // m2 (in-side inverse rotation of weight columns)
  float a00 =  ci * w00 + si * w01;
  float a01 = -si * w00 + ci * w01;
  float a10 =  ci * w10 + si * w11;
  float a11 = -si * w10 + ci * w11;

  // m3 (out-side inverse rotation, transposed form)
  float b00 = co * a00 - so * a10;
  float b10 = co * a01 - so * a11;
  float b01 = so * a00 + co * a10;
  float b11 = so * a01 + co * a11;

  // mask (in m3 / gathered coordinates)
  const float2 mk0 = *(const float2*)&mask[(size_t)(2 * m_out) * K_DIM + 2 * m_in];
  const float2 mk1 = *(const float2*)&mask[(size_t)(2 * m_out + 1) * K_DIM + 2 * m_in];
  b00 *= mk0.x; b10 *= mk0.y;
  b01 *= mk1.x; b11 *= mk1.y;

  // m4 (final out-pair rotation folded into columns)
  float c00 =  co * b00 + so * b01;
  float c10 =  co * b10 + so * b11;
  float c01 = -so * b00 + co * b01;
  float c11 = -so * b10 + co * b11;

  // input-side fold (rows scattered by in_mapping)
  float d00 = ci * c00 - si * c10;
  float d10 = si * c00 + ci * c10;
  float d01 = ci * c01 - si * c11;
  float d11 = si * c01 + ci * c11;

  w5t[(size_t)r0 * K_DIM + ia0] = f2bf(d00);
  w5t[(size_t)r0 * K_DIM + ia1] = f2bf(d10);
  w5t[(size_t)r1 * K_DIM + ia0] = f2bf(d01);
  w5t[(size_t)r1 * K_DIM + ia1] = f2bf(d11);
}

// ---------------- kernel 3: GEMM out = A(8192x1024) * W5(1024x4096), bf16 MFMA ----------------
// Block tile 256(M) x 128(N), 4 waves in 2x2, wave tile 128x64 (acc[8][4]).
// Rationale: LDS-read traffic is the structural floor of the m97 shape;
// FLOP per LDS byte goes 32 -> 42.7 with the 128x64 wave tile.

__device__ __forceinline__ void async_load16(const uint16_t* g, uint16_t* lds_wave_uniform) {
  __builtin_amdgcn_global_load_lds(
      (const __attribute__((address_space(1))) uint32_t*)g,
      (__attribute__((address_space(3))) uint32_t*)lds_wave_uniform,
      16, 0, 0);
}

__global__ __launch_bounds__(256, 2) void gemm_kernel(
    const uint16_t* __restrict__ A,   // (8192, 1024) bf16
    const uint16_t* __restrict__ BT,  // (4096, 1024) bf16 (W5^T, row=n, col=k)
    float* __restrict__ C)            // (8192, 4096) fp32
{
  __shared__ __align__(16) uint16_t As[256 * 32];  // 16 KB
  __shared__ __align__(16) uint16_t Bs[128 * 32];  //  8 KB

  const int tid  = threadIdx.x;
  const int wave = tid >> 6;
  const int lane = tid & 63;
  const int quad = lane >> 4;
  const int rr   = lane & 15;
  const int bn   = blockIdx.x;      // N tile [0,32)
  const int bm   = blockIdx.y;      // M tile [0,32)
  const int wm   = (wave >> 1) * 128;   // wave M offset within block: 0 or 128
  const int wn   = (wave & 1) * 64;     // wave N offset within block: 0 or 64

  f32x4 acc[8][4] = {};

  // staging: A = 1024 chunks of 16B (256 rows x 4), B = 512 chunks (128 rows x 4).
  // chunk c -> tile row c>>2, k-subchunk (c&3)*8 elements; LDS offset c*16 B.
  // group g covers chunks [g*256, g*256+256); within a group, thread tid takes
  // chunk g*256+tid, so each wave writes a contiguous 1 KB at base (g*256+wave*64)*16 B.
  const int row0 = tid >> 2;               // 0..63
  const int kb   = (lane & 3) * 8;         // element offset in row
  const uint16_t* gA0 = A  + (size_t)(bm * 256 + row0      ) * K_DIM + kb;
  const uint16_t* gA1 = A  + (size_t)(bm * 256 + row0 +  64) * K_DIM + kb;
  const uint16_t* gA2 = A  + (size_t)(bm * 256 + row0 + 128) * K_DIM + kb;
  const uint16_t* gA3 = A  + (size_t)(bm * 256 + row0 + 192) * K_DIM + kb;
  const uint16_t* gB0 = BT + (size_t)(bn * 128 + row0      ) * K_DIM + kb;
  const uint16_t* gB1 = BT + (size_t)(bn * 128 + row0 +  64) * K_DIM + kb;
  uint16_t* lA0 = &As[(0 * 256 + wave * 64) * 8];   // wave-uniform; HW adds lane*16B
  uint16_t* lA1 = &As[(1 * 256 + wave * 64) * 8];
  uint16_t* lA2 = &As[(2 * 256 + wave * 64) * 8];
  uint16_t* lA3 = &As[(3 * 256 + wave * 64) * 8];
  uint16_t* lB0 = &Bs[(0 * 256 + wave * 64) * 8];
  uint16_t* lB1 = &Bs[(1 * 256 + wave * 64) * 8];

  for (int k0 = 0; k0 < K_DIM; k0 += 32) {
    async_load16(gA0 + k0, lA0);
    async_load16(gA1 + k0, lA1);
    async_load16(gA2 + k0, lA2);
    async_load16(gA3 + k0, lA3);
    async_load16(gB0 + k0, lB0);
    async_load16(gB1 + k0, lB1);
    __syncthreads();   // compiler drains vmcnt before s_barrier

    bf16x8 af[8], bfr[4];
#pragma unroll
    for (int i = 0; i < 8; i++)
      af[i] = *reinterpret_cast<const bf16x8*>(&As[(wm + i * 16 + rr) * 32 + quad * 8]);
#pragma unroll
    for (int j = 0; j < 4; j++)
      bfr[j] = *reinterpret_cast<const bf16x8*>(&Bs[(wn + j * 16 + rr) * 32 + quad * 8]);

#pragma unroll
    for (int i = 0; i < 8; i++)
#pragma unroll
      for (int j = 0; j < 4; j++)
        acc[i][j] = __builtin_amdgcn_mfma_f32_16x16x32_bf16(af[i], bfr[j], acc[i][j], 0, 0, 0);

    __syncthreads();
  }

  // epilogue: D layout col = lane&15 (n), row = quad*4 + reg (m)
#pragma unroll
  for (int i = 0; i < 8; i++) {
#pragma unroll
    for (int j = 0; j < 4; j++) {
      const int colg = bn * 128 + wn + j * 16 + rr;
#pragma unroll
      for (int rg = 0; rg < 4; rg++) {
        const int rowg = bm * 256 + wm + i * 16 + quad * 4 + rg;
        C[(size_t)rowg * N_DIM + colg] = acc[i][j][rg];
      }
    }
  }
}

extern "C" void kernel_launch(void* const* d_in, const int* in_sizes, int n_in,
                              void* d_out, int out_size, void* d_ws, size_t ws_size,
                              hipStream_t stream) {
  const float* input      = (const float*)d_in[0];
  const float* weight     = (const float*)d_in[1];
  const float* mask       = (const float*)d_in[2];
  const float* in_scores  = (const float*)d_in[3];
  const float* out_scores = (const float*)d_in[4];
  const int*   in_mapping = (const int*)d_in[5];
  const int*   out_mapping= (const int*)d_in[6];
  // d_in[7] = out_mapping_reverse (folded away), d_in[8] = temperature (unused)
  float* out = (float*)d_out;

  uint16_t* a_bf16 = (uint16_t*)d_ws;                              // 8192*1024 bf16 = 16 MB
  uint16_t* w5t    = (uint16_t*)d_ws + (size_t)M_DIM * K_DIM;      // 4096*1024 bf16 = 8 MB

  convert_bf16_kernel<<<(M_DIM * K_DIM / 4 + 255) / 256, 256, 0, stream>>>(
      input, a_bf16, M_DIM * K_DIM / 4);

  build_w_kernel<<<(512 * 2048) / 256, 256, 0, stream>>>(
      weight, mask, in_scores, out_scores, in_mapping, out_mapping, w5t);

  dim3 grid(N_DIM / 128, M_DIM / 256);  // (32, 32)
  gemm_kernel<<<grid, 256, 0, stream>>>(a_bf16, w5t, out);
}

// Round 3
// 264.305 us; speedup vs baseline: 1.0471x; 1.0471x over previous
//
#include <hip/hip_runtime.h>
#include <hip/hip_bf16.h>
#include <stdint.h>

// Problem dims (fixed): B=4, S=2048, IN=1024, OUT=4096 -> M=8192, K=1024, N=4096
#define M_DIM 8192
#define K_DIM 1024
#define N_DIM 4096

typedef __bf16 bf16x8 __attribute__((ext_vector_type(8)));
typedef float  f32x4  __attribute__((ext_vector_type(4)));

__device__ __forceinline__ uint16_t f2bf(float f) {
  union { float f; uint32_t u; } x; x.f = f;
  uint32_t u = x.u;
  return (uint16_t)((u + 0x7FFFu + ((u >> 16) & 1u)) >> 16);  // RNE
}

// ---------------- kernel 1: input fp32 -> bf16 ----------------
__global__ __launch_bounds__(256) void convert_bf16_kernel(
    const float* __restrict__ in, uint16_t* __restrict__ out, int n4) {
  int i = blockIdx.x * 256 + threadIdx.x;
  if (i >= n4) return;
  float4 v = ((const float4*)in)[i];
  ushort4 o;
  o.x = f2bf(v.x); o.y = f2bf(v.y); o.z = f2bf(v.z); o.w = f2bf(v.w);
  ((ushort4*)out)[i] = o;
}

// ---------------- kernel 2: fold everything into W5^T (N x K) bf16 ----------------
// v2: one block per out-pair mo. All global access coalesced; the permutation
// scatter happens in LDS instead of L2 (R2 post-mortem: 4M scattered 2B global
// stores cost ~170 us as L2 read-modify-writes).
// Math chain identical to R1/R2 (validated: absmax 0.0156 vs threshold 0.0522).
__global__ __launch_bounds__(256) void build_w_kernel(
    const float* __restrict__ weight,      // (4096, 1024)
    const float* __restrict__ mask,        // (4096, 1024)
    const float* __restrict__ in_scores,   // (512)
    const float* __restrict__ out_scores,  // (2048)
    const int*   __restrict__ in_mapping,  // (1024)
    const int*   __restrict__ out_mapping, // (4096)
    uint16_t*    __restrict__ w5t)         // (4096, 1024) bf16: row=o, col=i
{
  __shared__ float    w0[K_DIM], w1[K_DIM];     // gathered weight rows (8 KB)
  __shared__ uint16_t o0[K_DIM], o1[K_DIM];     // scattered output rows (4 KB)

  const int mo = blockIdx.x;       // out-pair [0, 2048)
  const int t  = threadIdx.x;      // [0, 256)

  const int r0 = out_mapping[2 * mo];
  const int r1 = out_mapping[2 * mo + 1];

  // coalesced load of the two weight rows into LDS (256 threads x float4)
  ((float4*)w0)[t] = ((const float4*)(weight + (size_t)r0 * K_DIM))[t];
  ((float4*)w1)[t] = ((const float4*)(weight + (size_t)r1 * K_DIM))[t];

  const float ao = out_scores[mo];
  const float so = sinf(ao), co = cosf(ao);

  __syncthreads();

#pragma unroll
  for (int s = 0; s < 2; s++) {
    const int mi = t + s * 256;    // in-pair [0, 512)
    const float ai = in_scores[mi];
    const float si = sinf(ai), ci = cosf(ai);
    const int ia0 = in_mapping[2 * mi];
    const int ia1 = in_mapping[2 * mi + 1];

    const float w00 = w0[ia0], w01 = w0[ia1];
    const float w10 = w1[ia0], w11 = w1[ia1];

    // m2 (in-side inverse rotation of weight columns)
    float a00 =  ci * w00 + si * w01;
    float a01 = -si * w00 + ci * w01;
    float a10 =  ci * w10 + si * w11;
    float a11 = -si * w10 + ci * w11;

    // m3 (out-side inverse rotation, transposed form)
    float b00 = co * a00 - so * a10;
    float b10 = co * a01 - so * a11;
    float b01 = so * a00 + co * a10;
    float b11 = so * a01 + co * a11;

    // mask (gathered coordinates; coalesced float2 reads)
    const float2 mk0 = *(const float2*)&mask[(size_t)(2 * mo) * K_DIM + 2 * mi];
    const float2 mk1 = *(const float2*)&mask[(size_t)(2 * mo + 1) * K_DIM + 2 * mi];
    b00 *= mk0.x; b10 *= mk0.y;
    b01 *= mk1.x; b11 *= mk1.y;

    // m4 (final out-pair rotation folded into columns)
    float c00 =  co * b00 + so * b01;
    float c10 =  co * b10 + so * b11;
    float c01 = -so * b00 + co * b01;
    float c11 = -so * b10 + co * b11;

    // input-side fold (rows scattered by in_mapping) -> scatter into LDS
    o0[ia0] = f2bf(ci * c00 - si * c10);   // W5[ia0, r0]
    o0[ia1] = f2bf(si * c00 + ci * c10);   // W5[ia1, r0]
    o1[ia0] = f2bf(ci * c01 - si * c11);   // W5[ia0, r1]
    o1[ia1] = f2bf(si * c01 + ci * c11);   // W5[ia1, r1]
  }

  __syncthreads();

  // coalesced store of the two finished rows (256 threads x 8 B)
  ((uint2*)(w5t + (size_t)r0 * K_DIM))[t] = ((const uint2*)o0)[t];
  ((uint2*)(w5t + (size_t)r1 * K_DIM))[t] = ((const uint2*)o1)[t];
}

// ---------------- kernel 3: GEMM out = A(8192x1024) * W5(1024x4096), bf16 MFMA ----------------
// R1 configuration (128x128 tile, 4 waves, 64x64 wave tile): equal perf to the
// 256x128 variant but lower VGPR/LDS -> more occupancy headroom.

__device__ __forceinline__ void async_load16(const uint16_t* g, uint16_t* lds_wave_uniform) {
  __builtin_amdgcn_global_load_lds(
      (const __attribute__((address_space(1))) uint32_t*)g,
      (__attribute__((address_space(3))) uint32_t*)lds_wave_uniform,
      16, 0, 0);
}

__global__ __launch_bounds__(256, 2) void gemm_kernel(
    const uint16_t* __restrict__ A,   // (8192, 1024) bf16
    const uint16_t* __restrict__ BT,  // (4096, 1024) bf16 (W5^T, row=n, col=k)
    float* __restrict__ C)            // (8192, 4096) fp32
{
  __shared__ __align__(16) uint16_t As[128 * 32];
  __shared__ __align__(16) uint16_t Bs[128 * 32];

  const int tid  = threadIdx.x;
  const int wave = tid >> 6;
  const int lane = tid & 63;
  const int quad = lane >> 4;
  const int rr   = lane & 15;
  const int bn   = blockIdx.x;      // N tile [0,32)
  const int bm   = blockIdx.y;      // M tile [0,64)
  const int wm   = (wave >> 1) * 64;
  const int wn   = (wave & 1) * 64;

  f32x4 acc[4][4] = {};

  const int row0 = tid >> 2;               // 0..63
  const int kb   = (lane & 3) * 8;         // element offset in row
  const uint16_t* gA0 = A  + (size_t)(bm * 128 + row0) * K_DIM + kb;
  const uint16_t* gA1 = A  + (size_t)(bm * 128 + row0 + 64) * K_DIM + kb;
  const uint16_t* gB0 = BT + (size_t)(bn * 128 + row0) * K_DIM + kb;
  const uint16_t* gB1 = BT + (size_t)(bn * 128 + row0 + 64) * K_DIM + kb;
  uint16_t* lA0 = &As[wave * 512];          // wave-uniform; HW adds lane*16B
  uint16_t* lA1 = &As[2048 + wave * 512];
  uint16_t* lB0 = &Bs[wave * 512];
  uint16_t* lB1 = &Bs[2048 + wave * 512];

  for (int k0 = 0; k0 < K_DIM; k0 += 32) {
    async_load16(gA0 + k0, lA0);
    async_load16(gA1 + k0, lA1);
    async_load16(gB0 + k0, lB0);
    async_load16(gB1 + k0, lB1);
    __syncthreads();

    bf16x8 af[4], bfr[4];
#pragma unroll
    for (int i = 0; i < 4; i++)
      af[i] = *reinterpret_cast<const bf16x8*>(&As[(wm + i * 16 + rr) * 32 + quad * 8]);
#pragma unroll
    for (int j = 0; j < 4; j++)
      bfr[j] = *reinterpret_cast<const bf16x8*>(&Bs[(wn + j * 16 + rr) * 32 + quad * 8]);

#pragma unroll
    for (int i = 0; i < 4; i++)
#pragma unroll
      for (int j = 0; j < 4; j++)
        acc[i][j] = __builtin_amdgcn_mfma_f32_16x16x32_bf16(af[i], bfr[j], acc[i][j], 0, 0, 0);

    __syncthreads();
  }

  // epilogue: D layout col = lane&15 (n), row = quad*4 + reg (m)
#pragma unroll
  for (int i = 0; i < 4; i++) {
#pragma unroll
    for (int j = 0; j < 4; j++) {
      const int colg = bn * 128 + wn + j * 16 + rr;
#pragma unroll
      for (int rg = 0; rg < 4; rg++) {
        const int rowg = bm * 128 + wm + i * 16 + quad * 4 + rg;
        C[(size_t)rowg * N_DIM + colg] = acc[i][j][rg];
      }
    }
  }
}

extern "C" void kernel_launch(void* const* d_in, const int* in_sizes, int n_in,
                              void* d_out, int out_size, void* d_ws, size_t ws_size,
                              hipStream_t stream) {
  const float* input      = (const float*)d_in[0];
  const float* weight     = (const float*)d_in[1];
  const float* mask       = (const float*)d_in[2];
  const float* in_scores  = (const float*)d_in[3];
  const float* out_scores = (const float*)d_in[4];
  const int*   in_mapping = (const int*)d_in[5];
  const int*   out_mapping= (const int*)d_in[6];
  // d_in[7] = out_mapping_reverse (folded away), d_in[8] = temperature (unused)
  float* out = (float*)d_out;

  uint16_t* a_bf16 = (uint16_t*)d_ws;                              // 8192*1024 bf16 = 16 MB
  uint16_t* w5t    = (uint16_t*)d_ws + (size_t)M_DIM * K_DIM;      // 4096*1024 bf16 = 8 MB

  convert_bf16_kernel<<<(M_DIM * K_DIM / 4 + 255) / 256, 256, 0, stream>>>(
      input, a_bf16, M_DIM * K_DIM / 4);

  build_w_kernel<<<2048, 256, 0, stream>>>(
      weight, mask, in_scores, out_scores, in_mapping, out_mapping, w5t);

  dim3 grid(N_DIM / 128, M_DIM / 128);  // (32, 64)
  gemm_kernel<<<grid, 256, 0, stream>>>(a_bf16, w5t, out);
}

// Round 4
// 259.072 us; speedup vs baseline: 1.0682x; 1.0202x over previous
//
#include <hip/hip_runtime.h>
#include <hip/hip_bf16.h>
#include <stdint.h>

// Problem dims (fixed): B=4, S=2048, IN=1024, OUT=4096 -> M=8192, K=1024, N=4096
#define M_DIM 8192
#define K_DIM 1024
#define N_DIM 4096

typedef __bf16 bf16x8 __attribute__((ext_vector_type(8)));
typedef float  f32x4  __attribute__((ext_vector_type(4)));

__device__ __forceinline__ uint16_t f2bf(float f) {
  union { float f; uint32_t u; } x; x.f = f;
  uint32_t u = x.u;
  return (uint16_t)((u + 0x7FFFu + ((u >> 16) & 1u)) >> 16);  // RNE
}

// ---------------- kernel 1: input fp32 -> bf16 ----------------
__global__ __launch_bounds__(256) void convert_bf16_kernel(
    const float* __restrict__ in, uint16_t* __restrict__ out, int n4) {
  int i = blockIdx.x * 256 + threadIdx.x;
  if (i >= n4) return;
  float4 v = ((const float4*)in)[i];
  ushort4 o;
  o.x = f2bf(v.x); o.y = f2bf(v.y); o.z = f2bf(v.z); o.w = f2bf(v.w);
  ((ushort4*)out)[i] = o;
}

// ---------------- kernel 2: fold everything into W5^T (N x K) bf16 ----------------
// One block per out-pair mo; all global access coalesced, permutation scatter in LDS.
// Math chain validated R1-R3 (absmax 0.0156 vs threshold 0.0522).
__global__ __launch_bounds__(256) void build_w_kernel(
    const float* __restrict__ weight,      // (4096, 1024)
    const float* __restrict__ mask,        // (4096, 1024)
    const float* __restrict__ in_scores,   // (512)
    const float* __restrict__ out_scores,  // (2048)
    const int*   __restrict__ in_mapping,  // (1024)
    const int*   __restrict__ out_mapping, // (4096)
    uint16_t*    __restrict__ w5t)         // (4096, 1024) bf16: row=o, col=i
{
  __shared__ float    w0[K_DIM], w1[K_DIM];
  __shared__ uint16_t o0[K_DIM], o1[K_DIM];

  const int mo = blockIdx.x;       // out-pair [0, 2048)
  const int t  = threadIdx.x;      // [0, 256)

  const int r0 = out_mapping[2 * mo];
  const int r1 = out_mapping[2 * mo + 1];

  ((float4*)w0)[t] = ((const float4*)(weight + (size_t)r0 * K_DIM))[t];
  ((float4*)w1)[t] = ((const float4*)(weight + (size_t)r1 * K_DIM))[t];

  const float ao = out_scores[mo];
  const float so = sinf(ao), co = cosf(ao);

  __syncthreads();

#pragma unroll
  for (int s = 0; s < 2; s++) {
    const int mi = t + s * 256;
    const float ai = in_scores[mi];
    const float si = sinf(ai), ci = cosf(ai);
    const int ia0 = in_mapping[2 * mi];
    const int ia1 = in_mapping[2 * mi + 1];

    const float w00 = w0[ia0], w01 = w0[ia1];
    const float w10 = w1[ia0], w11 = w1[ia1];

    float a00 =  ci * w00 + si * w01;
    float a01 = -si * w00 + ci * w01;
    float a10 =  ci * w10 + si * w11;
    float a11 = -si * w10 + ci * w11;

    float b00 = co * a00 - so * a10;
    float b10 = co * a01 - so * a11;
    float b01 = so * a00 + co * a10;
    float b11 = so * a01 + co * a11;

    const float2 mk0 = *(const float2*)&mask[(size_t)(2 * mo) * K_DIM + 2 * mi];
    const float2 mk1 = *(const float2*)&mask[(size_t)(2 * mo + 1) * K_DIM + 2 * mi];
    b00 *= mk0.x; b10 *= mk0.y;
    b01 *= mk1.x; b11 *= mk1.y;

    float c00 =  co * b00 + so * b01;
    float c10 =  co * b10 + so * b11;
    float c01 = -so * b00 + co * b01;
    float c11 = -so * b10 + co * b11;

    o0[ia0] = f2bf(ci * c00 - si * c10);
    o0[ia1] = f2bf(si * c00 + ci * c10);
    o1[ia0] = f2bf(ci * c01 - si * c11);
    o1[ia1] = f2bf(si * c01 + ci * c11);
  }

  __syncthreads();

  ((uint2*)(w5t + (size_t)r0 * K_DIM))[t] = ((const uint2*)o0)[t];
  ((uint2*)(w5t + (size_t)r1 * K_DIM))[t] = ((const uint2*)o1)[t];
}

// ---------------- kernel 3: GEMM out = A(8192x1024) * W5(1024x4096), bf16 MFMA ----------------
// R4: BK=64 (16 K-iterations instead of 32 -> half the barrier-drain events),
// XOR bank swizzle on the staging SOURCE address so fragment ds_read_b128s stay
// conflict-free despite the 128 B (= 32-bank) row stride.
// LDS map: tile row r, k-group g (8 bf16 = 16 B) lives at chunk r*8 + (g ^ (r&7)).

__device__ __forceinline__ void async_load16(const uint16_t* g, uint16_t* lds_wave_uniform) {
  __builtin_amdgcn_global_load_lds(
      (const __attribute__((address_space(1))) uint32_t*)g,
      (__attribute__((address_space(3))) uint32_t*)lds_wave_uniform,
      16, 0, 0);
}

__global__ __launch_bounds__(256, 2) void gemm_kernel(
    const uint16_t* __restrict__ A,   // (8192, 1024) bf16
    const uint16_t* __restrict__ BT,  // (4096, 1024) bf16 (W5^T, row=n, col=k)
    float* __restrict__ C)            // (8192, 4096) fp32
{
  __shared__ __align__(16) uint16_t As[128 * 64];  // 16 KB
  __shared__ __align__(16) uint16_t Bs[128 * 64];  // 16 KB

  const int tid  = threadIdx.x;
  const int wave = tid >> 6;
  const int lane = tid & 63;
  const int quad = lane >> 4;
  const int rr   = lane & 15;
  const int bn   = blockIdx.x;      // N tile [0,32)
  const int bm   = blockIdx.y;      // M tile [0,64)
  const int wm   = (wave >> 1) * 64;
  const int wn   = (wave & 1) * 64;

  f32x4 acc[4][4] = {};

  // staging: per matrix 1024 chunks of 16 B per iter (128 rows x 8 k-groups).
  // group it in [0,4): chunk c = it*256 + tid -> row c>>3, stored k-group h = c&7,
  // which holds global k-group g = h ^ (row&7)  (XOR swizzle on the source).
  const uint16_t* gA[4];
  const uint16_t* gB[4];
  uint16_t* lA[4];
  uint16_t* lB[4];
#pragma unroll
  for (int it = 0; it < 4; it++) {
    const int c   = it * 256 + tid;
    const int row = c >> 3;
    const int h   = c & 7;
    const int g   = h ^ (row & 7);
    gA[it] = A  + (size_t)(bm * 128 + row) * K_DIM + g * 8;
    gB[it] = BT + (size_t)(bn * 128 + row) * K_DIM + g * 8;
    lA[it] = &As[(it * 256 + wave * 64) * 8];   // wave-uniform; HW adds lane*16B
    lB[it] = &Bs[(it * 256 + wave * 64) * 8];
  }

  for (int k0 = 0; k0 < K_DIM; k0 += 64) {
#pragma unroll
    for (int it = 0; it < 4; it++) {
      async_load16(gA[it] + k0, lA[it]);
      async_load16(gB[it] + k0, lB[it]);
    }
    __syncthreads();   // compiler drains vmcnt before s_barrier

    bf16x8 af[4][2], bfr[4][2];
#pragma unroll
    for (int i = 0; i < 4; i++) {
      const int r = wm + i * 16 + rr;
#pragma unroll
      for (int s = 0; s < 2; s++) {
        const int gk = s * 4 + quad;
        af[i][s] = *reinterpret_cast<const bf16x8*>(&As[(r * 8 + (gk ^ (r & 7))) * 8]);
      }
    }
#pragma unroll
    for (int j = 0; j < 4; j++) {
      const int r = wn + j * 16 + rr;
#pragma unroll
      for (int s = 0; s < 2; s++) {
        const int gk = s * 4 + quad;
        bfr[j][s] = *reinterpret_cast<const bf16x8*>(&Bs[(r * 8 + (gk ^ (r & 7))) * 8]);
      }
    }

#pragma unroll
    for (int s = 0; s < 2; s++)
#pragma unroll
      for (int i = 0; i < 4; i++)
#pragma unroll
        for (int j = 0; j < 4; j++)
          acc[i][j] = __builtin_amdgcn_mfma_f32_16x16x32_bf16(af[i][s], bfr[j][s], acc[i][j], 0, 0, 0);

    __syncthreads();
  }

  // epilogue: D layout col = lane&15 (n), row = quad*4 + reg (m)
#pragma unroll
  for (int i = 0; i < 4; i++) {
#pragma unroll
    for (int j = 0; j < 4; j++) {
      const int colg = bn * 128 + wn + j * 16 + rr;
#pragma unroll
      for (int rg = 0; rg < 4; rg++) {
        const int rowg = bm * 128 + wm + i * 16 + quad * 4 + rg;
        C[(size_t)rowg * N_DIM + colg] = acc[i][j][rg];
      }
    }
  }
}

extern "C" void kernel_launch(void* const* d_in, const int* in_sizes, int n_in,
                              void* d_out, int out_size, void* d_ws, size_t ws_size,
                              hipStream_t stream) {
  const float* input      = (const float*)d_in[0];
  const float* weight     = (const float*)d_in[1];
  const float* mask       = (const float*)d_in[2];
  const float* in_scores  = (const float*)d_in[3];
  const float* out_scores = (const float*)d_in[4];
  const int*   in_mapping = (const int*)d_in[5];
  const int*   out_mapping= (const int*)d_in[6];
  // d_in[7] = out_mapping_reverse (folded away), d_in[8] = temperature (unused)
  float* out = (float*)d_out;

  uint16_t* a_bf16 = (uint16_t*)d_ws;                              // 8192*1024 bf16 = 16 MB
  uint16_t* w5t    = (uint16_t*)d_ws + (size_t)M_DIM * K_DIM;      // 4096*1024 bf16 = 8 MB

  convert_bf16_kernel<<<(M_DIM * K_DIM / 4 + 255) / 256, 256, 0, stream>>>(
      input, a_bf16, M_DIM * K_DIM / 4);

  build_w_kernel<<<2048, 256, 0, stream>>>(
      weight, mask, in_scores, out_scores, in_mapping, out_mapping, w5t);

  dim3 grid(N_DIM / 128, M_DIM / 128);  // (32, 64)
  gemm_kernel<<<grid, 256, 0, stream>>>(a_bf16, w5t, out);
}